// Round 13
// baseline (198.747 us; speedup 1.0000x reference)
//
#include <hip/hip_runtime.h>
#include <hip/hip_fp16.h>

#define N_NODES 100000
#define N_EDGES 1600000
#define F 128
#define H 16
#define C 40
#define NH (N_NODES * H)
#define NBKT 391   // buckets of 256 nodes: ceil(100000/256)
#define ABLK 256   // partition blocks
#define EPB 6250   // edges per partition block (256*6250 = 1.6M exact)
#define CAP 6144   // per-bucket LDS capacity (mean 4096, ~32 sigma headroom)
#define PROJ_A 782 // proj blocks fused with pcount (nodes 0..50047)
#define PROJ_B 781 // proj blocks fused with fill  (nodes 50048..99999)
#define GCAP 3136  // per-half-bucket LDS capacity (mean 2048, ~24 sigma)
#define GBLK 782   // gout blocks: ceil(100000/128)

__device__ __forceinline__ float cvh(ushort u) {
  return __half2float(__ushort_as_half(u));
}
__device__ __forceinline__ ushort pkh(float f) {
  return __half_as_ushort(__float2half(f));
}
__device__ __forceinline__ unsigned pk2(float lo, float hi) {
  return (unsigned)pkh(lo) | ((unsigned)pkh(hi) << 16);
}

// ---- proj1 role body (shared by both fused kernels) ------------------------
__device__ __forceinline__ void proj1_body(
    int node0, int tid, float* xs, const float* __restrict__ x,
    const float* __restrict__ wn1, const float* __restrict__ ws1,
    const float* __restrict__ b1, __half* __restrict__ xn1h,
    __half* __restrict__ y1h16) {
  for (int i = tid; i < 64 * 32; i += 256) {
    int r = i >> 5, cv = i & 31;
    int n = node0 + r;
    float4 v = make_float4(0.f, 0.f, 0.f, 0.f);
    if (n < N_NODES) v = ((const float4*)x)[(size_t)n * 32 + cv];
    float* dp = &xs[r * 129 + cv * 4];
    dp[0] = v.x; dp[1] = v.y; dp[2] = v.z; dp[3] = v.w;
  }
  __syncthreads();

  const int wave = __builtin_amdgcn_readfirstlane(tid >> 6);
  const int lane = tid & 63;
  const int n = node0 + lane;
  const float* wmat = (wave < 2) ? wn1 : ws1;
  const int c0 = (wave & 1) * 8;

  float acc[8] = {0.f, 0.f, 0.f, 0.f, 0.f, 0.f, 0.f, 0.f};
  const float* xrow = &xs[lane * 129];
#pragma unroll 8
  for (int k = 0; k < F; ++k) {
    float xv = xrow[k];
    const float* wr = wmat + k * H + c0;
#pragma unroll
    for (int j = 0; j < 8; ++j) acc[j] += xv * wr[j];
  }
  if (n < N_NODES) {
    union { ushort u[8]; uint4 v; } pk;
    if (wave < 2) {
#pragma unroll
      for (int j = 0; j < 8; ++j) pk.u[j] = pkh(acc[j]);
      *(uint4*)&xn1h[n * H + c0] = pk.v;
    } else {
#pragma unroll
      for (int j = 0; j < 8; ++j) pk.u[j] = pkh(acc[j] + b1[c0 + j]);
      *(uint4*)&y1h16[n * H + c0] = pk.v;
    }
  }
}

// ---------------- kernel A: pcount (blocks 0..255) + proj1 half 1 -----------
__global__ __launch_bounds__(256) void k_cnt_proj(
    const float* __restrict__ x, const float* __restrict__ wn1,
    const float* __restrict__ ws1, const float* __restrict__ b1,
    const int* __restrict__ dst, int* __restrict__ pc,
    __half* __restrict__ xn1h, __half* __restrict__ y1h16) {
  __shared__ alignas(16) float xs[64 * 129];  // 33 KB; pcount aliases into it
  const int tid = threadIdx.x;
  if (blockIdx.x < ABLK) {
    int* cnt = (int*)xs;  // [NBKT]
    for (int i = tid; i < NBKT; i += 256) cnt[i] = 0;
    __syncthreads();
    const int e0 = blockIdx.x * EPB;
    for (int e = e0 + tid; e < e0 + EPB; e += 256)
      atomicAdd(&cnt[dst[e] >> 8], 1);
    __syncthreads();
    for (int i = tid; i < NBKT; i += 256)
      pc[blockIdx.x * NBKT + i] = cnt[i];
    return;
  }
  proj1_body((blockIdx.x - ABLK) * 64, tid, xs, x, wn1, ws1, b1, xn1h, y1h16);
}

// ---------------- CSR build 2a: per-bucket column scan (391 parallel blocks)
__global__ __launch_bounds__(256) void k_pscanA(int* __restrict__ pc,
                                                int* __restrict__ counts) {
  __shared__ int ls[256];
  const int t = blockIdx.x, tid = threadIdx.x;
  int v = pc[tid * NBKT + t];
  ls[tid] = v;
  __syncthreads();
  for (int off = 1; off < 256; off <<= 1) {
    int a = (tid >= off) ? ls[tid - off] : 0;
    __syncthreads();
    ls[tid] += a;
    __syncthreads();
  }
  pc[tid * NBKT + t] = ls[tid] - v;  // local exclusive base
  if (tid == 255) counts[t] = ls[255];
}

// ---------------- CSR build 2b: scan 391 bucket totals -> global starts -----
__global__ __launch_bounds__(512) void k_pscanB(const int* __restrict__ counts,
                                                int* __restrict__ starts) {
  __shared__ int ls[512];
  const int tid = threadIdx.x;
  int v = (tid < NBKT) ? counts[tid] : 0;
  ls[tid] = v;
  __syncthreads();
  for (int off = 1; off < 512; off <<= 1) {
    int a = (tid >= off) ? ls[tid - off] : 0;
    __syncthreads();
    ls[tid] += a;
    __syncthreads();
  }
  if (tid < NBKT) starts[tid] = ls[tid] - v;  // exclusive
}

// ---------------- kernel B: fill (blocks 0..255) + proj1 half 2 -------------
// pair = (dlocal<<17) | src  (dlocal<256 -> 8 bits; src<100000 -> 17 bits)
__global__ __launch_bounds__(256) void k_fill_proj(
    const float* __restrict__ x, const float* __restrict__ wn1,
    const float* __restrict__ ws1, const float* __restrict__ b1,
    const int* __restrict__ src, const int* __restrict__ dst,
    const int* __restrict__ pc, const int* __restrict__ starts,
    int* __restrict__ P, __half* __restrict__ xn1h,
    __half* __restrict__ y1h16) {
  __shared__ alignas(16) float xs[64 * 129];  // 33 KB; fill aliases into it
  const int tid = threadIdx.x;
  if (blockIdx.x < ABLK) {
    int* base_s = (int*)xs;          // [NBKT] absolute base
    int* cur = (int*)xs + NBKT;      // [NBKT]
    for (int i = tid; i < NBKT; i += 256) {
      base_s[i] = starts[i] + pc[blockIdx.x * NBKT + i];
      cur[i] = 0;
    }
    __syncthreads();
    const int e0 = blockIdx.x * EPB;
    for (int e = e0 + tid; e < e0 + EPB; e += 256) {
      int d = dst[e], s = src[e];
      int b = d >> 8;
      int off = atomicAdd(&cur[b], 1);
      P[base_s[b] + off] = ((d & 255) << 17) | s;
    }
    return;
  }
  proj1_body((PROJ_A + blockIdx.x - ABLK) * 64, tid, xs, x, wn1, ws1, b1,
             xn1h, y1h16);
}

// ---- accumulate one 32B fp16 row (2 x uint4) into float acc[16] ------------
#define ACC_ROW(ra, rb)                                                  \
  acc[0] += cvh((ushort)(ra.x)); acc[1] += cvh((ushort)(ra.x >> 16));    \
  acc[2] += cvh((ushort)(ra.y)); acc[3] += cvh((ushort)(ra.y >> 16));    \
  acc[4] += cvh((ushort)(ra.z)); acc[5] += cvh((ushort)(ra.z >> 16));    \
  acc[6] += cvh((ushort)(ra.w)); acc[7] += cvh((ushort)(ra.w >> 16));    \
  acc[8] += cvh((ushort)(rb.x)); acc[9] += cvh((ushort)(rb.x >> 16));    \
  acc[10] += cvh((ushort)(rb.y)); acc[11] += cvh((ushort)(rb.y >> 16));  \
  acc[12] += cvh((ushort)(rb.z)); acc[13] += cvh((ushort)(rb.z >> 16));  \
  acc[14] += cvh((ushort)(rb.w)); acc[15] += cvh((ushort)(rb.w >> 16));

// ---- gather loop: 2 threads/node (stride 2), ILP-8 main batch --------------
// 8 indices then 16 row-loads in flight -> ONE dependent round at mean deg 16.
#define GATHER_ROWS(idxtab, rowtab)                                        \
  {                                                                        \
    int e = lo + s;                                                        \
    for (; e + 14 < hi; e += 16) {                                         \
      int i0 = idxtab[e], i1 = idxtab[e + 2], i2 = idxtab[e + 4],          \
          i3 = idxtab[e + 6], i4 = idxtab[e + 8], i5 = idxtab[e + 10],     \
          i6 = idxtab[e + 12], i7 = idxtab[e + 14];                        \
      uint4 ra0 = rowtab[i0 * 2], rb0 = rowtab[i0 * 2 + 1];                \
      uint4 ra1 = rowtab[i1 * 2], rb1 = rowtab[i1 * 2 + 1];                \
      uint4 ra2 = rowtab[i2 * 2], rb2 = rowtab[i2 * 2 + 1];                \
      uint4 ra3 = rowtab[i3 * 2], rb3 = rowtab[i3 * 2 + 1];                \
      uint4 ra4 = rowtab[i4 * 2], rb4 = rowtab[i4 * 2 + 1];                \
      uint4 ra5 = rowtab[i5 * 2], rb5 = rowtab[i5 * 2 + 1];                \
      uint4 ra6 = rowtab[i6 * 2], rb6 = rowtab[i6 * 2 + 1];                \
      uint4 ra7 = rowtab[i7 * 2], rb7 = rowtab[i7 * 2 + 1];                \
      ACC_ROW(ra0, rb0) ACC_ROW(ra1, rb1) ACC_ROW(ra2, rb2)                \
      ACC_ROW(ra3, rb3) ACC_ROW(ra4, rb4) ACC_ROW(ra5, rb5)                \
      ACC_ROW(ra6, rb6) ACC_ROW(ra7, rb7)                                  \
    }                                                                      \
    for (; e + 6 < hi; e += 8) {                                           \
      int i0 = idxtab[e], i1 = idxtab[e + 2], i2 = idxtab[e + 4],          \
          i3 = idxtab[e + 6];                                              \
      uint4 ra0 = rowtab[i0 * 2], rb0 = rowtab[i0 * 2 + 1];                \
      uint4 ra1 = rowtab[i1 * 2], rb1 = rowtab[i1 * 2 + 1];                \
      uint4 ra2 = rowtab[i2 * 2], rb2 = rowtab[i2 * 2 + 1];                \
      uint4 ra3 = rowtab[i3 * 2], rb3 = rowtab[i3 * 2 + 1];                \
      ACC_ROW(ra0, rb0) ACC_ROW(ra1, rb1) ACC_ROW(ra2, rb2)                \
      ACC_ROW(ra3, rb3)                                                    \
    }                                                                      \
    for (; e < hi; e += 2) {                                               \
      int i0 = idxtab[e];                                                  \
      uint4 ra0 = rowtab[i0 * 2], rb0 = rowtab[i0 * 2 + 1];                \
      ACC_ROW(ra0, rb0)                                                    \
    }                                                                      \
  }

// ------- bucket sort + layer-1 gather fused ---------------------------------
__global__ __launch_bounds__(512) void k_gsort1(
    const int* __restrict__ starts, const int* __restrict__ counts,
    int* __restrict__ P, int* __restrict__ A,
    const __half* __restrict__ xn1h, const __half* __restrict__ y1h16,
    __half* __restrict__ h16) {
  __shared__ int pbuf[CAP];
  __shared__ int sbuf[CAP];
  __shared__ int h[256];
  __shared__ int hstart[256];
  __shared__ int cur[256];
  const int t = blockIdx.x, tid = threadIdx.x;
  const int st = starts[t];
  int cnt = counts[t];
  if (cnt > CAP) cnt = CAP;  // ~impossible; guards LDS
  for (int i = tid; i < cnt; i += 512) pbuf[i] = P[st + i];
  if (tid < 256) h[tid] = 0;
  __syncthreads();
  for (int i = tid; i < cnt; i += 512) atomicAdd(&h[pbuf[i] >> 17], 1);
  __syncthreads();
  int v = (tid < 256) ? h[tid] : 0;
  for (int off = 1; off < 256; off <<= 1) {
    int a = (tid < 256 && tid >= off) ? h[tid - off] : 0;
    __syncthreads();
    if (tid < 256) h[tid] += a;
    __syncthreads();
  }
  if (tid < 256) {
    int incl = h[tid];
    hstart[tid] = incl - v;
    cur[tid] = incl - v;
    int node = t * 256 + tid;
    if (node < N_NODES) A[node] = st + incl;
  }
  __syncthreads();
  for (int i = tid; i < cnt; i += 512) {
    int pv = pbuf[i];
    int nl = pv >> 17;
    int p = atomicAdd(&cur[nl], 1);
    sbuf[p] = pv & 0x1FFFF;
  }
  __syncthreads();
  // write sorted srclist back for k_gout2 (coalesced)
  for (int i = tid; i < cnt; i += 512) P[st + i] = sbuf[i];

  // ---- gather phase: 2 threads per node, edges from LDS ----
  const int nl = tid >> 1, s = tid & 1;
  const int n = t * 256 + nl;
  if (n >= N_NODES) return;  // no further barriers
  const int lo = hstart[nl], hi = cur[nl];  // cur[nl] == end after scatter
  const uint4* xr = (const uint4*)xn1h;  // 2 uint4 per 32B row
  float acc[16];
#pragma unroll
  for (int i = 0; i < 16; ++i) acc[i] = 0.f;
  GATHER_ROWS(sbuf, xr)
#pragma unroll
  for (int i = 0; i < 16; ++i) acc[i] += __shfl_xor(acc[i], 1);
  if (s == 0) {
    const float rd = 1.0f / fmaxf((float)(hi - lo), 1.0f);
    uint4 ya = ((const uint4*)y1h16)[n * 2];
    uint4 yb = ((const uint4*)y1h16)[n * 2 + 1];
    float o[16];
    o[0] = fmaxf(cvh((ushort)(ya.x)) + acc[0] * rd, 0.f);
    o[1] = fmaxf(cvh((ushort)(ya.x >> 16)) + acc[1] * rd, 0.f);
    o[2] = fmaxf(cvh((ushort)(ya.y)) + acc[2] * rd, 0.f);
    o[3] = fmaxf(cvh((ushort)(ya.y >> 16)) + acc[3] * rd, 0.f);
    o[4] = fmaxf(cvh((ushort)(ya.z)) + acc[4] * rd, 0.f);
    o[5] = fmaxf(cvh((ushort)(ya.z >> 16)) + acc[5] * rd, 0.f);
    o[6] = fmaxf(cvh((ushort)(ya.w)) + acc[6] * rd, 0.f);
    o[7] = fmaxf(cvh((ushort)(ya.w >> 16)) + acc[7] * rd, 0.f);
    o[8] = fmaxf(cvh((ushort)(yb.x)) + acc[8] * rd, 0.f);
    o[9] = fmaxf(cvh((ushort)(yb.x >> 16)) + acc[9] * rd, 0.f);
    o[10] = fmaxf(cvh((ushort)(yb.y)) + acc[10] * rd, 0.f);
    o[11] = fmaxf(cvh((ushort)(yb.y >> 16)) + acc[11] * rd, 0.f);
    o[12] = fmaxf(cvh((ushort)(yb.z)) + acc[12] * rd, 0.f);
    o[13] = fmaxf(cvh((ushort)(yb.z >> 16)) + acc[13] * rd, 0.f);
    o[14] = fmaxf(cvh((ushort)(yb.w)) + acc[14] * rd, 0.f);
    o[15] = fmaxf(cvh((ushort)(yb.w >> 16)) + acc[15] * rd, 0.f);
    uint4 wa, wb;
    wa.x = pk2(o[0], o[1]);   wa.y = pk2(o[2], o[3]);
    wa.z = pk2(o[4], o[5]);   wa.w = pk2(o[6], o[7]);
    wb.x = pk2(o[8], o[9]);   wb.y = pk2(o[10], o[11]);
    wb.z = pk2(o[12], o[13]); wb.w = pk2(o[14], o[15]);
    ((uint4*)h16)[n * 2] = wa;
    ((uint4*)h16)[n * 2 + 1] = wb;
  }
}

// ------- gather layer 2 + output GEMM, LDS-resident srclist -----------------
__global__ __launch_bounds__(256) void k_gout2(
    const __half* __restrict__ h16, const int* __restrict__ A,
    const int* __restrict__ srclist, const float* __restrict__ wn2,
    const float* __restrict__ ws2, const float* __restrict__ b2,
    float* __restrict__ out) {
  __shared__ int sb[GCAP];
  __shared__ int Aloc[129];
  __shared__ float wns[H * C];
  __shared__ float wss[H * C];
  __shared__ float bs[C];
  const int tid = threadIdx.x;
  const int n0 = blockIdx.x * 128;
  for (int i = tid; i < H * C; i += 256) {
    wns[i] = wn2[i];
    wss[i] = ws2[i];
  }
  if (tid < C) bs[tid] = b2[tid];
  if (tid == 0) Aloc[0] = (n0 == 0) ? 0 : A[n0 - 1];
  if (tid < 128) {
    int nn = n0 + tid;
    if (nn < N_NODES) Aloc[tid + 1] = A[nn];
  }
  __syncthreads();
  const int lastv = (n0 + 127 < N_NODES) ? 127 : (N_NODES - 1 - n0);
  const int base = Aloc[0];
  int cnt = Aloc[lastv + 1] - base;
  if (cnt > GCAP) cnt = GCAP;  // ~impossible; guards LDS
  for (int i = tid; i < cnt; i += 256) sb[i] = srclist[base + i];
  __syncthreads();

  const int nl = tid >> 1, s = tid & 1;
  const int n = n0 + nl;
  if (n >= N_NODES) return;  // no further barriers
  int lo = Aloc[nl] - base, hi = Aloc[nl + 1] - base;
  if (hi > cnt) hi = cnt;
  const uint4* hr = (const uint4*)h16;
  float acc[16];
#pragma unroll
  for (int i = 0; i < 16; ++i) acc[i] = 0.f;
  GATHER_ROWS(sb, hr)
#pragma unroll
  for (int i = 0; i < 16; ++i) acc[i] += __shfl_xor(acc[i], 1);

  // epilogue: this thread computes cols [s*20, s*20+20)
  const float rd = 1.0f / fmaxf((float)(hi - lo), 1.0f);
  uint4 ha = hr[n * 2], hb = hr[n * 2 + 1];
  float hv[16];
  hv[0] = cvh((ushort)(ha.x));  hv[1] = cvh((ushort)(ha.x >> 16));
  hv[2] = cvh((ushort)(ha.y));  hv[3] = cvh((ushort)(ha.y >> 16));
  hv[4] = cvh((ushort)(ha.z));  hv[5] = cvh((ushort)(ha.z >> 16));
  hv[6] = cvh((ushort)(ha.w));  hv[7] = cvh((ushort)(ha.w >> 16));
  hv[8] = cvh((ushort)(hb.x));  hv[9] = cvh((ushort)(hb.x >> 16));
  hv[10] = cvh((ushort)(hb.y)); hv[11] = cvh((ushort)(hb.y >> 16));
  hv[12] = cvh((ushort)(hb.z)); hv[13] = cvh((ushort)(hb.z >> 16));
  hv[14] = cvh((ushort)(hb.w)); hv[15] = cvh((ushort)(hb.w >> 16));
  const int c0 = s * 20;
  float o[20];
#pragma unroll
  for (int j = 0; j < 20; ++j) o[j] = bs[c0 + j];
#pragma unroll
  for (int k = 0; k < H; ++k) {
    float a = hv[k];
    const float* wr = &wss[k * C + c0];
#pragma unroll
    for (int j = 0; j < 20; ++j) o[j] += a * wr[j];
  }
#pragma unroll
  for (int k = 0; k < H; ++k) {
    float m = acc[k] * rd;
    const float* wr = &wns[k * C + c0];
#pragma unroll
    for (int j = 0; j < 20; ++j) o[j] += m * wr[j];
  }
  float* orow = &out[(size_t)n * C + c0];
#pragma unroll
  for (int q = 0; q < 5; ++q)
    *(float4*)&orow[q * 4] =
        make_float4(o[q * 4], o[q * 4 + 1], o[q * 4 + 2], o[q * 4 + 3]);
}

extern "C" void kernel_launch(void* const* d_in, const int* in_sizes, int n_in,
                              void* d_out, int out_size, void* d_ws,
                              size_t ws_size, hipStream_t stream) {
  const float* x = (const float*)d_in[0];
  const int* src = (const int*)d_in[1];
  const int* dst = (const int*)d_in[2];
  const float* wn1 = (const float*)d_in[3];
  const float* ws1 = (const float*)d_in[4];
  const float* b1 = (const float*)d_in[5];
  const float* wn2 = (const float*)d_in[6];
  const float* ws2 = (const float*)d_in[7];
  const float* b2 = (const float*)d_in[8];
  float* out = (float*)d_out;

  // xn1 (fp16, 3.2MB) lives in d_out (consumed by k_gsort1 before k_gout2
  // writes d_out).
  __half* xn1h = (__half*)out;

  // ws layout (float offsets), 13.2 MB total (same byte footprint):
  //   [0, 100000)              A: CSR end offsets (int)
  //   [100000, 100391)         starts (int)
  //   [100391, 100782)         counts (int)
  //   [102400, 102400+E)       P: packed pairs -> sorted srclist in place (int)
  //   [102400+E, +NH/2)        y1 (fp16, NH halves)
  //   [102400+E+NH/2, +NH/2)   h  (fp16, NH halves)
  //   pc (int[256*391] = 400 KB) OVERLAYS the h region (dead after fill).
  float* wsp = (float*)d_ws;
  int* A = (int*)wsp;
  int* starts = (int*)wsp + 100000;
  int* counts = (int*)wsp + 100391;
  int* P = (int*)(wsp + 102400);
  __half* y1h16 = (__half*)(wsp + 102400 + N_EDGES);
  __half* h16 = (__half*)(wsp + 102400 + N_EDGES + NH / 2);
  int* pc = (int*)(wsp + 102400 + N_EDGES + NH / 2);  // overlay on h16

  k_cnt_proj<<<ABLK + PROJ_A, 256, 0, stream>>>(x, wn1, ws1, b1, dst, pc,
                                                xn1h, y1h16);
  k_pscanA<<<NBKT, 256, 0, stream>>>(pc, counts);
  k_pscanB<<<1, 512, 0, stream>>>(counts, starts);
  k_fill_proj<<<ABLK + PROJ_B, 256, 0, stream>>>(x, wn1, ws1, b1, src, dst, pc,
                                                 starts, P, xn1h, y1h16);
  k_gsort1<<<NBKT, 512, 0, stream>>>(starts, counts, P, A, xn1h, y1h16, h16);
  k_gout2<<<GBLK, 256, 0, stream>>>(h16, A, P, wn2, ws2, b2, out);
}

// Round 14
// 194.121 us; speedup vs baseline: 1.0238x; 1.0238x over previous
//
#include <hip/hip_runtime.h>
#include <hip/hip_fp16.h>

#define N_NODES 100000
#define N_EDGES 1600000
#define F 128
#define H 16
#define C 40
#define NH (N_NODES * H)
#define NBKT 391   // buckets of 256 nodes: ceil(100000/256)
#define ABLK 256   // partition blocks
#define EPB 6250   // edges per partition block (256*6250 = 1.6M exact)
#define CAP 6144   // per-bucket LDS capacity (mean 4096, ~32 sigma headroom)
#define PROJ_A 782 // proj blocks fused with pcount (nodes 0..50047)
#define PROJ_B 781 // proj blocks fused with fill  (nodes 50048..99999)
#define GCAP 3136  // per-half-bucket LDS capacity (mean 2048, ~24 sigma)
#define GBLK 782   // gout blocks: ceil(100000/128)

__device__ __forceinline__ float cvh(ushort u) {
  return __half2float(__ushort_as_half(u));
}
__device__ __forceinline__ ushort pkh(float f) {
  return __half_as_ushort(__float2half(f));
}
__device__ __forceinline__ unsigned pk2(float lo, float hi) {
  return (unsigned)pkh(lo) | ((unsigned)pkh(hi) << 16);
}

// ---- proj1 role body (shared by both fused kernels) ------------------------
__device__ __forceinline__ void proj1_body(
    int node0, int tid, float* xs, const float* __restrict__ x,
    const float* __restrict__ wn1, const float* __restrict__ ws1,
    const float* __restrict__ b1, __half* __restrict__ xn1h,
    __half* __restrict__ y1h16) {
  for (int i = tid; i < 64 * 32; i += 256) {
    int r = i >> 5, cv = i & 31;
    int n = node0 + r;
    float4 v = make_float4(0.f, 0.f, 0.f, 0.f);
    if (n < N_NODES) v = ((const float4*)x)[(size_t)n * 32 + cv];
    float* dp = &xs[r * 129 + cv * 4];
    dp[0] = v.x; dp[1] = v.y; dp[2] = v.z; dp[3] = v.w;
  }
  __syncthreads();

  const int wave = __builtin_amdgcn_readfirstlane(tid >> 6);
  const int lane = tid & 63;
  const int n = node0 + lane;
  const float* wmat = (wave < 2) ? wn1 : ws1;
  const int c0 = (wave & 1) * 8;

  float acc[8] = {0.f, 0.f, 0.f, 0.f, 0.f, 0.f, 0.f, 0.f};
  const float* xrow = &xs[lane * 129];
#pragma unroll 8
  for (int k = 0; k < F; ++k) {
    float xv = xrow[k];
    const float* wr = wmat + k * H + c0;
#pragma unroll
    for (int j = 0; j < 8; ++j) acc[j] += xv * wr[j];
  }
  if (n < N_NODES) {
    union { ushort u[8]; uint4 v; } pk;
    if (wave < 2) {
#pragma unroll
      for (int j = 0; j < 8; ++j) pk.u[j] = pkh(acc[j]);
      *(uint4*)&xn1h[n * H + c0] = pk.v;
    } else {
#pragma unroll
      for (int j = 0; j < 8; ++j) pk.u[j] = pkh(acc[j] + b1[c0 + j]);
      *(uint4*)&y1h16[n * H + c0] = pk.v;
    }
  }
}

// ---------------- kernel A: pcount (blocks 0..255) + proj1 half 1 -----------
__global__ __launch_bounds__(256) void k_cnt_proj(
    const float* __restrict__ x, const float* __restrict__ wn1,
    const float* __restrict__ ws1, const float* __restrict__ b1,
    const int* __restrict__ dst, int* __restrict__ pc,
    __half* __restrict__ xn1h, __half* __restrict__ y1h16) {
  __shared__ alignas(16) float xs[64 * 129];  // 33 KB; pcount aliases into it
  const int tid = threadIdx.x;
  if (blockIdx.x < ABLK) {
    int* cnt = (int*)xs;  // [NBKT]
    for (int i = tid; i < NBKT; i += 256) cnt[i] = 0;
    __syncthreads();
    const int e0 = blockIdx.x * EPB;
    for (int e = e0 + tid; e < e0 + EPB; e += 256)
      atomicAdd(&cnt[dst[e] >> 8], 1);
    __syncthreads();
    for (int i = tid; i < NBKT; i += 256)
      pc[blockIdx.x * NBKT + i] = cnt[i];
    return;
  }
  proj1_body((blockIdx.x - ABLK) * 64, tid, xs, x, wn1, ws1, b1, xn1h, y1h16);
}

// ---------------- CSR build 2a: per-bucket column scan (391 parallel blocks)
__global__ __launch_bounds__(256) void k_pscanA(int* __restrict__ pc,
                                                int* __restrict__ counts) {
  __shared__ int ls[256];
  const int t = blockIdx.x, tid = threadIdx.x;
  int v = pc[tid * NBKT + t];
  ls[tid] = v;
  __syncthreads();
  for (int off = 1; off < 256; off <<= 1) {
    int a = (tid >= off) ? ls[tid - off] : 0;
    __syncthreads();
    ls[tid] += a;
    __syncthreads();
  }
  pc[tid * NBKT + t] = ls[tid] - v;  // local exclusive base
  if (tid == 255) counts[t] = ls[255];
}

// ---------------- CSR build 2b: scan 391 bucket totals -> global starts -----
__global__ __launch_bounds__(512) void k_pscanB(const int* __restrict__ counts,
                                                int* __restrict__ starts) {
  __shared__ int ls[512];
  const int tid = threadIdx.x;
  int v = (tid < NBKT) ? counts[tid] : 0;
  ls[tid] = v;
  __syncthreads();
  for (int off = 1; off < 512; off <<= 1) {
    int a = (tid >= off) ? ls[tid - off] : 0;
    __syncthreads();
    ls[tid] += a;
    __syncthreads();
  }
  if (tid < NBKT) starts[tid] = ls[tid] - v;  // exclusive
}

// ---------------- kernel B: fill (blocks 0..255) + proj1 half 2 -------------
// pair = (dlocal<<17) | src  (dlocal<256 -> 8 bits; src<100000 -> 17 bits)
__global__ __launch_bounds__(256) void k_fill_proj(
    const float* __restrict__ x, const float* __restrict__ wn1,
    const float* __restrict__ ws1, const float* __restrict__ b1,
    const int* __restrict__ src, const int* __restrict__ dst,
    const int* __restrict__ pc, const int* __restrict__ starts,
    int* __restrict__ P, __half* __restrict__ xn1h,
    __half* __restrict__ y1h16) {
  __shared__ alignas(16) float xs[64 * 129];  // 33 KB; fill aliases into it
  const int tid = threadIdx.x;
  if (blockIdx.x < ABLK) {
    int* base_s = (int*)xs;          // [NBKT] absolute base
    int* cur = (int*)xs + NBKT;      // [NBKT]
    for (int i = tid; i < NBKT; i += 256) {
      base_s[i] = starts[i] + pc[blockIdx.x * NBKT + i];
      cur[i] = 0;
    }
    __syncthreads();
    const int e0 = blockIdx.x * EPB;
    for (int e = e0 + tid; e < e0 + EPB; e += 256) {
      int d = dst[e], s = src[e];
      int b = d >> 8;
      int off = atomicAdd(&cur[b], 1);
      P[base_s[b] + off] = ((d & 255) << 17) | s;
    }
    return;
  }
  proj1_body((PROJ_A + blockIdx.x - ABLK) * 64, tid, xs, x, wn1, ws1, b1,
             xn1h, y1h16);
}

// ---- accumulate one 32B fp16 row (2 x uint4) into float acc[16] ------------
#define ACC_ROW(ra, rb)                                                  \
  acc[0] += cvh((ushort)(ra.x)); acc[1] += cvh((ushort)(ra.x >> 16));    \
  acc[2] += cvh((ushort)(ra.y)); acc[3] += cvh((ushort)(ra.y >> 16));    \
  acc[4] += cvh((ushort)(ra.z)); acc[5] += cvh((ushort)(ra.z >> 16));    \
  acc[6] += cvh((ushort)(ra.w)); acc[7] += cvh((ushort)(ra.w >> 16));    \
  acc[8] += cvh((ushort)(rb.x)); acc[9] += cvh((ushort)(rb.x >> 16));    \
  acc[10] += cvh((ushort)(rb.y)); acc[11] += cvh((ushort)(rb.y >> 16));  \
  acc[12] += cvh((ushort)(rb.z)); acc[13] += cvh((ushort)(rb.z >> 16));  \
  acc[14] += cvh((ushort)(rb.w)); acc[15] += cvh((ushort)(rb.w >> 16));

// ---- gather loop: 2 threads/node (stride 2), ILP-4 batch (round-12 proven;
// ILP-8 regressed: VGPR pressure for a path most nodes never take) ----------
#define GATHER_ROWS(idxtab, rowtab)                                        \
  {                                                                        \
    int e = lo + s;                                                        \
    for (; e + 6 < hi; e += 8) {                                           \
      int i0 = idxtab[e], i1 = idxtab[e + 2], i2 = idxtab[e + 4],          \
          i3 = idxtab[e + 6];                                              \
      uint4 ra0 = rowtab[i0 * 2], rb0 = rowtab[i0 * 2 + 1];                \
      uint4 ra1 = rowtab[i1 * 2], rb1 = rowtab[i1 * 2 + 1];                \
      uint4 ra2 = rowtab[i2 * 2], rb2 = rowtab[i2 * 2 + 1];                \
      uint4 ra3 = rowtab[i3 * 2], rb3 = rowtab[i3 * 2 + 1];                \
      ACC_ROW(ra0, rb0) ACC_ROW(ra1, rb1) ACC_ROW(ra2, rb2)                \
      ACC_ROW(ra3, rb3)                                                    \
    }                                                                      \
    for (; e < hi; e += 2) {                                               \
      int i0 = idxtab[e];                                                  \
      uint4 ra0 = rowtab[i0 * 2], rb0 = rowtab[i0 * 2 + 1];                \
      ACC_ROW(ra0, rb0)                                                    \
    }                                                                      \
  }

// ------- bucket sort + layer-1 gather fused ---------------------------------
__global__ __launch_bounds__(512) void k_gsort1(
    const int* __restrict__ starts, const int* __restrict__ counts,
    int* __restrict__ P, int* __restrict__ A,
    const __half* __restrict__ xn1h, const __half* __restrict__ y1h16,
    __half* __restrict__ h16) {
  __shared__ int pbuf[CAP];
  __shared__ int sbuf[CAP];
  __shared__ int h[256];
  __shared__ int hstart[256];
  __shared__ int cur[256];
  const int t = blockIdx.x, tid = threadIdx.x;
  const int st = starts[t];
  int cnt = counts[t];
  if (cnt > CAP) cnt = CAP;  // ~impossible; guards LDS
  for (int i = tid; i < cnt; i += 512) pbuf[i] = P[st + i];
  if (tid < 256) h[tid] = 0;
  __syncthreads();
  for (int i = tid; i < cnt; i += 512) atomicAdd(&h[pbuf[i] >> 17], 1);
  __syncthreads();
  int v = (tid < 256) ? h[tid] : 0;
  for (int off = 1; off < 256; off <<= 1) {
    int a = (tid < 256 && tid >= off) ? h[tid - off] : 0;
    __syncthreads();
    if (tid < 256) h[tid] += a;
    __syncthreads();
  }
  if (tid < 256) {
    int incl = h[tid];
    hstart[tid] = incl - v;
    cur[tid] = incl - v;
    int node = t * 256 + tid;
    if (node < N_NODES) A[node] = st + incl;
  }
  __syncthreads();
  for (int i = tid; i < cnt; i += 512) {
    int pv = pbuf[i];
    int nl = pv >> 17;
    int p = atomicAdd(&cur[nl], 1);
    sbuf[p] = pv & 0x1FFFF;
  }
  __syncthreads();
  // write sorted srclist back for k_gout2 (coalesced)
  for (int i = tid; i < cnt; i += 512) P[st + i] = sbuf[i];

  // ---- gather phase: 2 threads per node, edges from LDS ----
  const int nl = tid >> 1, s = tid & 1;
  const int n = t * 256 + nl;
  if (n >= N_NODES) return;  // no further barriers
  const int lo = hstart[nl], hi = cur[nl];  // cur[nl] == end after scatter
  const uint4* xr = (const uint4*)xn1h;  // 2 uint4 per 32B row
  float acc[16];
#pragma unroll
  for (int i = 0; i < 16; ++i) acc[i] = 0.f;
  GATHER_ROWS(sbuf, xr)
#pragma unroll
  for (int i = 0; i < 16; ++i) acc[i] += __shfl_xor(acc[i], 1);
  if (s == 0) {
    const float rd = 1.0f / fmaxf((float)(hi - lo), 1.0f);
    uint4 ya = ((const uint4*)y1h16)[n * 2];
    uint4 yb = ((const uint4*)y1h16)[n * 2 + 1];
    float o[16];
    o[0] = fmaxf(cvh((ushort)(ya.x)) + acc[0] * rd, 0.f);
    o[1] = fmaxf(cvh((ushort)(ya.x >> 16)) + acc[1] * rd, 0.f);
    o[2] = fmaxf(cvh((ushort)(ya.y)) + acc[2] * rd, 0.f);
    o[3] = fmaxf(cvh((ushort)(ya.y >> 16)) + acc[3] * rd, 0.f);
    o[4] = fmaxf(cvh((ushort)(ya.z)) + acc[4] * rd, 0.f);
    o[5] = fmaxf(cvh((ushort)(ya.z >> 16)) + acc[5] * rd, 0.f);
    o[6] = fmaxf(cvh((ushort)(ya.w)) + acc[6] * rd, 0.f);
    o[7] = fmaxf(cvh((ushort)(ya.w >> 16)) + acc[7] * rd, 0.f);
    o[8] = fmaxf(cvh((ushort)(yb.x)) + acc[8] * rd, 0.f);
    o[9] = fmaxf(cvh((ushort)(yb.x >> 16)) + acc[9] * rd, 0.f);
    o[10] = fmaxf(cvh((ushort)(yb.y)) + acc[10] * rd, 0.f);
    o[11] = fmaxf(cvh((ushort)(yb.y >> 16)) + acc[11] * rd, 0.f);
    o[12] = fmaxf(cvh((ushort)(yb.z)) + acc[12] * rd, 0.f);
    o[13] = fmaxf(cvh((ushort)(yb.z >> 16)) + acc[13] * rd, 0.f);
    o[14] = fmaxf(cvh((ushort)(yb.w)) + acc[14] * rd, 0.f);
    o[15] = fmaxf(cvh((ushort)(yb.w >> 16)) + acc[15] * rd, 0.f);
    uint4 wa, wb;
    wa.x = pk2(o[0], o[1]);   wa.y = pk2(o[2], o[3]);
    wa.z = pk2(o[4], o[5]);   wa.w = pk2(o[6], o[7]);
    wb.x = pk2(o[8], o[9]);   wb.y = pk2(o[10], o[11]);
    wb.z = pk2(o[12], o[13]); wb.w = pk2(o[14], o[15]);
    ((uint4*)h16)[n * 2] = wa;
    ((uint4*)h16)[n * 2 + 1] = wb;
  }
}

// ------- gather layer 2 + output GEMM, LDS-resident srclist -----------------
__global__ __launch_bounds__(256) void k_gout2(
    const __half* __restrict__ h16, const int* __restrict__ A,
    const int* __restrict__ srclist, const float* __restrict__ wn2,
    const float* __restrict__ ws2, const float* __restrict__ b2,
    float* __restrict__ out) {
  __shared__ int sb[GCAP];
  __shared__ int Aloc[129];
  __shared__ float wns[H * C];
  __shared__ float wss[H * C];
  __shared__ float bs[C];
  const int tid = threadIdx.x;
  const int n0 = blockIdx.x * 128;
  for (int i = tid; i < H * C; i += 256) {
    wns[i] = wn2[i];
    wss[i] = ws2[i];
  }
  if (tid < C) bs[tid] = b2[tid];
  if (tid == 0) Aloc[0] = (n0 == 0) ? 0 : A[n0 - 1];
  if (tid < 128) {
    int nn = n0 + tid;
    if (nn < N_NODES) Aloc[tid + 1] = A[nn];
  }
  __syncthreads();
  const int lastv = (n0 + 127 < N_NODES) ? 127 : (N_NODES - 1 - n0);
  const int base = Aloc[0];
  int cnt = Aloc[lastv + 1] - base;
  if (cnt > GCAP) cnt = GCAP;  // ~impossible; guards LDS
  for (int i = tid; i < cnt; i += 256) sb[i] = srclist[base + i];
  __syncthreads();

  const int nl = tid >> 1, s = tid & 1;
  const int n = n0 + nl;
  if (n >= N_NODES) return;  // no further barriers
  int lo = Aloc[nl] - base, hi = Aloc[nl + 1] - base;
  if (hi > cnt) hi = cnt;
  const uint4* hr = (const uint4*)h16;
  float acc[16];
#pragma unroll
  for (int i = 0; i < 16; ++i) acc[i] = 0.f;
  GATHER_ROWS(sb, hr)
#pragma unroll
  for (int i = 0; i < 16; ++i) acc[i] += __shfl_xor(acc[i], 1);

  // epilogue: this thread computes cols [s*20, s*20+20)
  const float rd = 1.0f / fmaxf((float)(hi - lo), 1.0f);
  uint4 ha = hr[n * 2], hb = hr[n * 2 + 1];
  float hv[16];
  hv[0] = cvh((ushort)(ha.x));  hv[1] = cvh((ushort)(ha.x >> 16));
  hv[2] = cvh((ushort)(ha.y));  hv[3] = cvh((ushort)(ha.y >> 16));
  hv[4] = cvh((ushort)(ha.z));  hv[5] = cvh((ushort)(ha.z >> 16));
  hv[6] = cvh((ushort)(ha.w));  hv[7] = cvh((ushort)(ha.w >> 16));
  hv[8] = cvh((ushort)(hb.x));  hv[9] = cvh((ushort)(hb.x >> 16));
  hv[10] = cvh((ushort)(hb.y)); hv[11] = cvh((ushort)(hb.y >> 16));
  hv[12] = cvh((ushort)(hb.z)); hv[13] = cvh((ushort)(hb.z >> 16));
  hv[14] = cvh((ushort)(hb.w)); hv[15] = cvh((ushort)(hb.w >> 16));
  const int c0 = s * 20;
  float o[20];
#pragma unroll
  for (int j = 0; j < 20; ++j) o[j] = bs[c0 + j];
#pragma unroll
  for (int k = 0; k < H; ++k) {
    float a = hv[k];
    const float* wr = &wss[k * C + c0];
#pragma unroll
    for (int j = 0; j < 20; ++j) o[j] += a * wr[j];
  }
#pragma unroll
  for (int k = 0; k < H; ++k) {
    float m = acc[k] * rd;
    const float* wr = &wns[k * C + c0];
#pragma unroll
    for (int j = 0; j < 20; ++j) o[j] += m * wr[j];
  }
  float* orow = &out[(size_t)n * C + c0];
#pragma unroll
  for (int q = 0; q < 5; ++q)
    *(float4*)&orow[q * 4] =
        make_float4(o[q * 4], o[q * 4 + 1], o[q * 4 + 2], o[q * 4 + 3]);
}

extern "C" void kernel_launch(void* const* d_in, const int* in_sizes, int n_in,
                              void* d_out, int out_size, void* d_ws,
                              size_t ws_size, hipStream_t stream) {
  const float* x = (const float*)d_in[0];
  const int* src = (const int*)d_in[1];
  const int* dst = (const int*)d_in[2];
  const float* wn1 = (const float*)d_in[3];
  const float* ws1 = (const float*)d_in[4];
  const float* b1 = (const float*)d_in[5];
  const float* wn2 = (const float*)d_in[6];
  const float* ws2 = (const float*)d_in[7];
  const float* b2 = (const float*)d_in[8];
  float* out = (float*)d_out;

  // xn1 (fp16, 3.2MB) lives in d_out (consumed by k_gsort1 before k_gout2
  // writes d_out).
  __half* xn1h = (__half*)out;

  // ws layout (float offsets), 13.2 MB total (same byte footprint):
  //   [0, 100000)              A: CSR end offsets (int)
  //   [100000, 100391)         starts (int)
  //   [100391, 100782)         counts (int)
  //   [102400, 102400+E)       P: packed pairs -> sorted srclist in place (int)
  //   [102400+E, +NH/2)        y1 (fp16, NH halves)
  //   [102400+E+NH/2, +NH/2)   h  (fp16, NH halves)
  //   pc (int[256*391] = 400 KB) OVERLAYS the h region (dead after fill).
  float* wsp = (float*)d_ws;
  int* A = (int*)wsp;
  int* starts = (int*)wsp + 100000;
  int* counts = (int*)wsp + 100391;
  int* P = (int*)(wsp + 102400);
  __half* y1h16 = (__half*)(wsp + 102400 + N_EDGES);
  __half* h16 = (__half*)(wsp + 102400 + N_EDGES + NH / 2);
  int* pc = (int*)(wsp + 102400 + N_EDGES + NH / 2);  // overlay on h16

  k_cnt_proj<<<ABLK + PROJ_A, 256, 0, stream>>>(x, wn1, ws1, b1, dst, pc,
                                                xn1h, y1h16);
  k_pscanA<<<NBKT, 256, 0, stream>>>(pc, counts);
  k_pscanB<<<1, 512, 0, stream>>>(counts, starts);
  k_fill_proj<<<ABLK + PROJ_B, 256, 0, stream>>>(x, wn1, ws1, b1, src, dst, pc,
                                                 starts, P, xn1h, y1h16);
  k_gsort1<<<NBKT, 512, 0, stream>>>(starts, counts, P, A, xn1h, y1h16, h16);
  k_gout2<<<GBLK, 256, 0, stream>>>(h16, A, P, wn2, ws2, b2, out);
}

// Round 15
// 189.190 us; speedup vs baseline: 1.0505x; 1.0261x over previous
//
#include <hip/hip_runtime.h>
#include <hip/hip_fp16.h>

#define N_NODES 100000
#define N_EDGES 1600000
#define F 128
#define H 16
#define C 40
#define NH (N_NODES * H)
#define NBKT 391   // buckets of 256 nodes: ceil(100000/256)
#define ABLK 256   // partition blocks
#define EPB 6250   // edges per partition block (256*6250 = 1.6M exact)
#define CAP 6144   // per-bucket LDS capacity (mean 4096, ~32 sigma headroom)
#define PROJB 1563 // proj1 blocks: ceil(100000/64)
#define GCAP 3136  // per-half-bucket LDS capacity (mean 2048, ~24 sigma)
#define GBLK 782   // gout blocks: ceil(100000/128)

__device__ __forceinline__ float cvh(ushort u) {
  return __half2float(__ushort_as_half(u));
}
__device__ __forceinline__ ushort pkh(float f) {
  return __half_as_ushort(__float2half(f));
}
__device__ __forceinline__ unsigned pk2(float lo, float hi) {
  return (unsigned)pkh(lo) | ((unsigned)pkh(hi) << 16);
}

// ---------------- CSR build 1: per-block bucket rows (plain stores) ---------
// Standalone (round-12 shape): tiny, so the scan chain starts ASAP; proj work
// all lives in k_fill_proj where it hides the fill role's latency.
__global__ __launch_bounds__(256) void k_pcount(const int* __restrict__ dst,
                                                int* __restrict__ pc) {
  __shared__ int cnt[NBKT];
  for (int i = threadIdx.x; i < NBKT; i += 256) cnt[i] = 0;
  __syncthreads();
  const int e0 = blockIdx.x * EPB;
  for (int e = e0 + threadIdx.x; e < e0 + EPB; e += 256)
    atomicAdd(&cnt[dst[e] >> 8], 1);
  __syncthreads();
  for (int i = threadIdx.x; i < NBKT; i += 256)
    pc[blockIdx.x * NBKT + i] = cnt[i];
}

// ---------------- CSR build 2a: per-bucket column scan (391 parallel blocks)
__global__ __launch_bounds__(256) void k_pscanA(int* __restrict__ pc,
                                                int* __restrict__ counts) {
  __shared__ int ls[256];
  const int t = blockIdx.x, tid = threadIdx.x;
  int v = pc[tid * NBKT + t];
  ls[tid] = v;
  __syncthreads();
  for (int off = 1; off < 256; off <<= 1) {
    int a = (tid >= off) ? ls[tid - off] : 0;
    __syncthreads();
    ls[tid] += a;
    __syncthreads();
  }
  pc[tid * NBKT + t] = ls[tid] - v;  // local exclusive base
  if (tid == 255) counts[t] = ls[255];
}

// ---------------- CSR build 2b: scan 391 bucket totals -> global starts -----
__global__ __launch_bounds__(512) void k_pscanB(const int* __restrict__ counts,
                                                int* __restrict__ starts) {
  __shared__ int ls[512];
  const int tid = threadIdx.x;
  int v = (tid < NBKT) ? counts[tid] : 0;
  ls[tid] = v;
  __syncthreads();
  for (int off = 1; off < 512; off <<= 1) {
    int a = (tid >= off) ? ls[tid - off] : 0;
    __syncthreads();
    ls[tid] += a;
    __syncthreads();
  }
  if (tid < NBKT) starts[tid] = ls[tid] - v;  // exclusive
}

// ---------------- CSR fill (blocks 0..255) fused with proj1 (rest) ----------
// pair = (dlocal<<17) | src  (dlocal<256 -> 8 bits; src<100000 -> 17 bits)
__global__ __launch_bounds__(256) void k_fill_proj(
    const float* __restrict__ x, const float* __restrict__ wn1,
    const float* __restrict__ ws1, const float* __restrict__ b1,
    const int* __restrict__ src, const int* __restrict__ dst,
    const int* __restrict__ pc, const int* __restrict__ starts,
    int* __restrict__ P, __half* __restrict__ xn1h,
    __half* __restrict__ y1h16) {
  __shared__ alignas(16) float xs[64 * 129];  // 33 KB; fill aliases into it
  const int tid = threadIdx.x;
  if (blockIdx.x < ABLK) {
    int* base_s = (int*)xs;          // [NBKT] absolute base
    int* cur = (int*)xs + NBKT;      // [NBKT]
    for (int i = tid; i < NBKT; i += 256) {
      base_s[i] = starts[i] + pc[blockIdx.x * NBKT + i];
      cur[i] = 0;
    }
    __syncthreads();
    const int e0 = blockIdx.x * EPB;
    for (int e = e0 + tid; e < e0 + EPB; e += 256) {
      int d = dst[e], s = src[e];
      int b = d >> 8;
      int off = atomicAdd(&cur[b], 1);
      P[base_s[b] + off] = ((d & 255) << 17) | s;
    }
    return;
  }
  // ---- proj1 role ----
  const int node0 = (blockIdx.x - ABLK) * 64;
  for (int i = tid; i < 64 * 32; i += 256) {
    int r = i >> 5, cv = i & 31;
    int n = node0 + r;
    float4 v = make_float4(0.f, 0.f, 0.f, 0.f);
    if (n < N_NODES) v = ((const float4*)x)[(size_t)n * 32 + cv];
    float* dp = &xs[r * 129 + cv * 4];
    dp[0] = v.x; dp[1] = v.y; dp[2] = v.z; dp[3] = v.w;
  }
  __syncthreads();

  const int wave = __builtin_amdgcn_readfirstlane(tid >> 6);
  const int lane = tid & 63;
  const int n = node0 + lane;
  const float* wmat = (wave < 2) ? wn1 : ws1;
  const int c0 = (wave & 1) * 8;

  float acc[8] = {0.f, 0.f, 0.f, 0.f, 0.f, 0.f, 0.f, 0.f};
  const float* xrow = &xs[lane * 129];
#pragma unroll 8
  for (int k = 0; k < F; ++k) {
    float xv = xrow[k];
    const float* wr = wmat + k * H + c0;
#pragma unroll
    for (int j = 0; j < 8; ++j) acc[j] += xv * wr[j];
  }
  if (n < N_NODES) {
    union { ushort u[8]; uint4 v; } pk;
    if (wave < 2) {
#pragma unroll
      for (int j = 0; j < 8; ++j) pk.u[j] = pkh(acc[j]);
      *(uint4*)&xn1h[n * H + c0] = pk.v;
    } else {
#pragma unroll
      for (int j = 0; j < 8; ++j) pk.u[j] = pkh(acc[j] + b1[c0 + j]);
      *(uint4*)&y1h16[n * H + c0] = pk.v;
    }
  }
}

// ---- accumulate one 32B fp16 row (2 x uint4) into float acc[16] ------------
#define ACC_ROW(ra, rb)                                                  \
  acc[0] += cvh((ushort)(ra.x)); acc[1] += cvh((ushort)(ra.x >> 16));    \
  acc[2] += cvh((ushort)(ra.y)); acc[3] += cvh((ushort)(ra.y >> 16));    \
  acc[4] += cvh((ushort)(ra.z)); acc[5] += cvh((ushort)(ra.z >> 16));    \
  acc[6] += cvh((ushort)(ra.w)); acc[7] += cvh((ushort)(ra.w >> 16));    \
  acc[8] += cvh((ushort)(rb.x)); acc[9] += cvh((ushort)(rb.x >> 16));    \
  acc[10] += cvh((ushort)(rb.y)); acc[11] += cvh((ushort)(rb.y >> 16));  \
  acc[12] += cvh((ushort)(rb.z)); acc[13] += cvh((ushort)(rb.z >> 16));  \
  acc[14] += cvh((ushort)(rb.w)); acc[15] += cvh((ushort)(rb.w >> 16));

// ---- gather loop: 2 threads/node (stride 2), ILP-4 batch (round-12 proven;
// ILP-8 regressed: VGPR pressure for a path most nodes never take) ----------
#define GATHER_ROWS(idxtab, rowtab)                                        \
  {                                                                        \
    int e = lo + s;                                                        \
    for (; e + 6 < hi; e += 8) {                                           \
      int i0 = idxtab[e], i1 = idxtab[e + 2], i2 = idxtab[e + 4],          \
          i3 = idxtab[e + 6];                                              \
      uint4 ra0 = rowtab[i0 * 2], rb0 = rowtab[i0 * 2 + 1];                \
      uint4 ra1 = rowtab[i1 * 2], rb1 = rowtab[i1 * 2 + 1];                \
      uint4 ra2 = rowtab[i2 * 2], rb2 = rowtab[i2 * 2 + 1];                \
      uint4 ra3 = rowtab[i3 * 2], rb3 = rowtab[i3 * 2 + 1];                \
      ACC_ROW(ra0, rb0) ACC_ROW(ra1, rb1) ACC_ROW(ra2, rb2)                \
      ACC_ROW(ra3, rb3)                                                    \
    }                                                                      \
    for (; e < hi; e += 2) {                                               \
      int i0 = idxtab[e];                                                  \
      uint4 ra0 = rowtab[i0 * 2], rb0 = rowtab[i0 * 2 + 1];                \
      ACC_ROW(ra0, rb0)                                                    \
    }                                                                      \
  }

// ------- bucket sort + layer-1 gather fused ---------------------------------
// CHANGE vs round 12: two-pass histogram over GLOBAL P (P is L2-resident,
// coalesced) instead of staging into a pbuf — LDS 52->27.6 KB, so blocks/CU
// 3->4, waves/CU 24->32 (+33% concurrency for the latency-bound gather).
__global__ __launch_bounds__(512) void k_gsort1(
    const int* __restrict__ starts, const int* __restrict__ counts,
    int* __restrict__ P, int* __restrict__ A,
    const __half* __restrict__ xn1h, const __half* __restrict__ y1h16,
    __half* __restrict__ h16) {
  __shared__ int sbuf[CAP];
  __shared__ int h[256];
  __shared__ int hstart[256];
  __shared__ int cur[256];
  const int t = blockIdx.x, tid = threadIdx.x;
  const int st = starts[t];
  int cnt = counts[t];
  if (cnt > CAP) cnt = CAP;  // ~impossible; guards LDS
  if (tid < 256) h[tid] = 0;
  __syncthreads();
  // pass 1: histogram from global P (coalesced, L2-hit)
  for (int i = tid; i < cnt; i += 512) atomicAdd(&h[P[st + i] >> 17], 1);
  __syncthreads();
  int v = (tid < 256) ? h[tid] : 0;
  for (int off = 1; off < 256; off <<= 1) {
    int a = (tid < 256 && tid >= off) ? h[tid - off] : 0;
    __syncthreads();
    if (tid < 256) h[tid] += a;
    __syncthreads();
  }
  if (tid < 256) {
    int incl = h[tid];
    hstart[tid] = incl - v;
    cur[tid] = incl - v;
    int node = t * 256 + tid;
    if (node < N_NODES) A[node] = st + incl;
  }
  __syncthreads();
  // pass 2: scatter from global P into sorted LDS list
  for (int i = tid; i < cnt; i += 512) {
    int pv = P[st + i];
    int nl = pv >> 17;
    int p = atomicAdd(&cur[nl], 1);
    sbuf[p] = pv & 0x1FFFF;
  }
  __syncthreads();
  // write sorted srclist back for k_gout2 (coalesced)
  for (int i = tid; i < cnt; i += 512) P[st + i] = sbuf[i];

  // ---- gather phase: 2 threads per node, edges from LDS ----
  const int nl = tid >> 1, s = tid & 1;
  const int n = t * 256 + nl;
  if (n >= N_NODES) return;  // no further barriers
  const int lo = hstart[nl], hi = cur[nl];  // cur[nl] == end after scatter
  const uint4* xr = (const uint4*)xn1h;  // 2 uint4 per 32B row
  float acc[16];
#pragma unroll
  for (int i = 0; i < 16; ++i) acc[i] = 0.f;
  GATHER_ROWS(sbuf, xr)
#pragma unroll
  for (int i = 0; i < 16; ++i) acc[i] += __shfl_xor(acc[i], 1);
  if (s == 0) {
    const float rd = 1.0f / fmaxf((float)(hi - lo), 1.0f);
    uint4 ya = ((const uint4*)y1h16)[n * 2];
    uint4 yb = ((const uint4*)y1h16)[n * 2 + 1];
    float o[16];
    o[0] = fmaxf(cvh((ushort)(ya.x)) + acc[0] * rd, 0.f);
    o[1] = fmaxf(cvh((ushort)(ya.x >> 16)) + acc[1] * rd, 0.f);
    o[2] = fmaxf(cvh((ushort)(ya.y)) + acc[2] * rd, 0.f);
    o[3] = fmaxf(cvh((ushort)(ya.y >> 16)) + acc[3] * rd, 0.f);
    o[4] = fmaxf(cvh((ushort)(ya.z)) + acc[4] * rd, 0.f);
    o[5] = fmaxf(cvh((ushort)(ya.z >> 16)) + acc[5] * rd, 0.f);
    o[6] = fmaxf(cvh((ushort)(ya.w)) + acc[6] * rd, 0.f);
    o[7] = fmaxf(cvh((ushort)(ya.w >> 16)) + acc[7] * rd, 0.f);
    o[8] = fmaxf(cvh((ushort)(yb.x)) + acc[8] * rd, 0.f);
    o[9] = fmaxf(cvh((ushort)(yb.x >> 16)) + acc[9] * rd, 0.f);
    o[10] = fmaxf(cvh((ushort)(yb.y)) + acc[10] * rd, 0.f);
    o[11] = fmaxf(cvh((ushort)(yb.y >> 16)) + acc[11] * rd, 0.f);
    o[12] = fmaxf(cvh((ushort)(yb.z)) + acc[12] * rd, 0.f);
    o[13] = fmaxf(cvh((ushort)(yb.z >> 16)) + acc[13] * rd, 0.f);
    o[14] = fmaxf(cvh((ushort)(yb.w)) + acc[14] * rd, 0.f);
    o[15] = fmaxf(cvh((ushort)(yb.w >> 16)) + acc[15] * rd, 0.f);
    uint4 wa, wb;
    wa.x = pk2(o[0], o[1]);   wa.y = pk2(o[2], o[3]);
    wa.z = pk2(o[4], o[5]);   wa.w = pk2(o[6], o[7]);
    wb.x = pk2(o[8], o[9]);   wb.y = pk2(o[10], o[11]);
    wb.z = pk2(o[12], o[13]); wb.w = pk2(o[14], o[15]);
    ((uint4*)h16)[n * 2] = wa;
    ((uint4*)h16)[n * 2 + 1] = wb;
  }
}

// ------- gather layer 2 + output GEMM, LDS-resident srclist -----------------
__global__ __launch_bounds__(256) void k_gout2(
    const __half* __restrict__ h16, const int* __restrict__ A,
    const int* __restrict__ srclist, const float* __restrict__ wn2,
    const float* __restrict__ ws2, const float* __restrict__ b2,
    float* __restrict__ out) {
  __shared__ int sb[GCAP];
  __shared__ int Aloc[129];
  __shared__ float wns[H * C];
  __shared__ float wss[H * C];
  __shared__ float bs[C];
  const int tid = threadIdx.x;
  const int n0 = blockIdx.x * 128;
  for (int i = tid; i < H * C; i += 256) {
    wns[i] = wn2[i];
    wss[i] = ws2[i];
  }
  if (tid < C) bs[tid] = b2[tid];
  if (tid == 0) Aloc[0] = (n0 == 0) ? 0 : A[n0 - 1];
  if (tid < 128) {
    int nn = n0 + tid;
    if (nn < N_NODES) Aloc[tid + 1] = A[nn];
  }
  __syncthreads();
  const int lastv = (n0 + 127 < N_NODES) ? 127 : (N_NODES - 1 - n0);
  const int base = Aloc[0];
  int cnt = Aloc[lastv + 1] - base;
  if (cnt > GCAP) cnt = GCAP;  // ~impossible; guards LDS
  for (int i = tid; i < cnt; i += 256) sb[i] = srclist[base + i];
  __syncthreads();

  const int nl = tid >> 1, s = tid & 1;
  const int n = n0 + nl;
  if (n >= N_NODES) return;  // no further barriers
  int lo = Aloc[nl] - base, hi = Aloc[nl + 1] - base;
  if (hi > cnt) hi = cnt;
  const uint4* hr = (const uint4*)h16;
  float acc[16];
#pragma unroll
  for (int i = 0; i < 16; ++i) acc[i] = 0.f;
  GATHER_ROWS(sb, hr)
#pragma unroll
  for (int i = 0; i < 16; ++i) acc[i] += __shfl_xor(acc[i], 1);

  // epilogue: this thread computes cols [s*20, s*20+20)
  const float rd = 1.0f / fmaxf((float)(hi - lo), 1.0f);
  uint4 ha = hr[n * 2], hb = hr[n * 2 + 1];
  float hv[16];
  hv[0] = cvh((ushort)(ha.x));  hv[1] = cvh((ushort)(ha.x >> 16));
  hv[2] = cvh((ushort)(ha.y));  hv[3] = cvh((ushort)(ha.y >> 16));
  hv[4] = cvh((ushort)(ha.z));  hv[5] = cvh((ushort)(ha.z >> 16));
  hv[6] = cvh((ushort)(ha.w));  hv[7] = cvh((ushort)(ha.w >> 16));
  hv[8] = cvh((ushort)(hb.x));  hv[9] = cvh((ushort)(hb.x >> 16));
  hv[10] = cvh((ushort)(hb.y)); hv[11] = cvh((ushort)(hb.y >> 16));
  hv[12] = cvh((ushort)(hb.z)); hv[13] = cvh((ushort)(hb.z >> 16));
  hv[14] = cvh((ushort)(hb.w)); hv[15] = cvh((ushort)(hb.w >> 16));
  const int c0 = s * 20;
  float o[20];
#pragma unroll
  for (int j = 0; j < 20; ++j) o[j] = bs[c0 + j];
#pragma unroll
  for (int k = 0; k < H; ++k) {
    float a = hv[k];
    const float* wr = &wss[k * C + c0];
#pragma unroll
    for (int j = 0; j < 20; ++j) o[j] += a * wr[j];
  }
#pragma unroll
  for (int k = 0; k < H; ++k) {
    float m = acc[k] * rd;
    const float* wr = &wns[k * C + c0];
#pragma unroll
    for (int j = 0; j < 20; ++j) o[j] += m * wr[j];
  }
  float* orow = &out[(size_t)n * C + c0];
#pragma unroll
  for (int q = 0; q < 5; ++q)
    *(float4*)&orow[q * 4] =
        make_float4(o[q * 4], o[q * 4 + 1], o[q * 4 + 2], o[q * 4 + 3]);
}

extern "C" void kernel_launch(void* const* d_in, const int* in_sizes, int n_in,
                              void* d_out, int out_size, void* d_ws,
                              size_t ws_size, hipStream_t stream) {
  const float* x = (const float*)d_in[0];
  const int* src = (const int*)d_in[1];
  const int* dst = (const int*)d_in[2];
  const float* wn1 = (const float*)d_in[3];
  const float* ws1 = (const float*)d_in[4];
  const float* b1 = (const float*)d_in[5];
  const float* wn2 = (const float*)d_in[6];
  const float* ws2 = (const float*)d_in[7];
  const float* b2 = (const float*)d_in[8];
  float* out = (float*)d_out;

  // xn1 (fp16, 3.2MB) lives in d_out (consumed by k_gsort1 before k_gout2
  // writes d_out).
  __half* xn1h = (__half*)out;

  // ws layout (float offsets), 13.2 MB total (same byte footprint):
  //   [0, 100000)              A: CSR end offsets (int)
  //   [100000, 100391)         starts (int)
  //   [100391, 100782)         counts (int)
  //   [102400, 102400+E)       P: packed pairs -> sorted srclist in place (int)
  //   [102400+E, +NH/2)        y1 (fp16, NH halves)
  //   [102400+E+NH/2, +NH/2)   h  (fp16, NH halves)
  //   pc (int[256*391] = 400 KB) OVERLAYS the h region (dead after fill).
  float* wsp = (float*)d_ws;
  int* A = (int*)wsp;
  int* starts = (int*)wsp + 100000;
  int* counts = (int*)wsp + 100391;
  int* P = (int*)(wsp + 102400);
  __half* y1h16 = (__half*)(wsp + 102400 + N_EDGES);
  __half* h16 = (__half*)(wsp + 102400 + N_EDGES + NH / 2);
  int* pc = (int*)(wsp + 102400 + N_EDGES + NH / 2);  // overlay on h16

  k_pcount<<<ABLK, 256, 0, stream>>>(dst, pc);
  k_pscanA<<<NBKT, 256, 0, stream>>>(pc, counts);
  k_pscanB<<<1, 512, 0, stream>>>(counts, starts);
  k_fill_proj<<<ABLK + PROJB, 256, 0, stream>>>(x, wn1, ws1, b1, src, dst, pc,
                                                starts, P, xn1h, y1h16);
  k_gsort1<<<NBKT, 512, 0, stream>>>(starts, counts, P, A, xn1h, y1h16, h16);
  k_gout2<<<GBLK, 256, 0, stream>>>(h16, A, P, wn2, ws2, b2, out);
}